// Round 10
// baseline (109.332 us; speedup 1.0000x reference)
//
#include <hip/hip_runtime.h>
#include <math.h>

#define N_      8
#define HO      62
#define XT_STR  200                  // halves per col (192 rows + 8 pad)
// LDS float offsets:
//   xt   : 20 cols * 200 halves = 2000 floats @ 0
//   bufS : 2 rounds * 1536 floats ([ti][px*12+wv])  @ 2000
//   vbuf : 128 ch * 20 floats                        @ 5072
#define BUFS_OFF 2000
#define VB_OFF   5072
#define LDS_F    7632                // 30528 B

typedef _Float16 half8  __attribute__((ext_vector_type(8)));
typedef _Float16 half4v __attribute__((ext_vector_type(4)));
typedef _Float16 half2v __attribute__((ext_vector_type(2)));
typedef float    f32x4  __attribute__((ext_vector_type(4)));

#define W_TUPLES 12288               // 8 ti * 8 mt * 3 ks * 64 lanes
#define W_PAIRS  (W_TUPLES * 4)      // 49152 half2 outputs
#define WPACK_BYTES (W_TUPLES * 16)

// ---- one-time weight repack with permuted K, element-pair parallel ---------
// out half index = (((ti*8+mt)*3+ks)*64 + lane)*8 + j ; kperm = ks*32+q*8+j;
// physical k = rem*3 + kw with kw = kperm/24, rem = kperm%24. Zero for kperm>=72.
__global__ __launch_bounds__(256)
void repack_w(const float* __restrict__ w, _Float16* __restrict__ wp) {
    int o = blockIdx.x * 256 + threadIdx.x;        // one half2 per thread
    if (o >= W_PAIRS) return;
    int j2   = (o & 3) * 2;
    int lane = (o >> 2) & 63;
    int g3   = o >> 8;                             // timt*3 + ks
    int ks   = g3 % 3;
    int timt = g3 / 3;                             // ti*8 + mt
    int q    = lane >> 4;
    int cl   = lane & 15;
    int ti   = timt >> 3;
    int mt   = timt & 7;
    const float* wr = w + (size_t)(ti * 128 + mt * 16 + cl) * 72;
    int kp = ks * 32 + q * 8 + j2;
    float v0 = 0.f, v1 = 0.f;
    if (kp < 72)     { int kw = kp / 24;        int rm = kp - kw * 24;       v0 = wr[rm * 3 + kw]; }
    if (kp + 1 < 72) { int kw = (kp + 1) / 24;  int rm = (kp + 1) - kw * 24; v1 = wr[rm * 3 + kw]; }
    half2v h = { (_Float16)v0, (_Float16)v1 };
    ((half2v*)wp)[o] = h;
}

// WG = 512 threads = 8 waves; 16 output px (one 16-col chunk of one row).
// Wave wv owns M-tile mt=wv (16 ch). Lane: px = l&15, q = l>>4.
// Conv: 3 ks * 8 ti MFMAs (f32_16x16x32_f16); acc[ti] = uhat stays in regs.
// A-loads SOFTWARE-PIPELINED one ks-stage ahead (ks=0 issued before staging).
// C-layout: ch = wv*16 + q*4 + r  ->  to = wv*2+(q>>1), do = (q&1)*4+r.
// Routing in this layout: squash/agreement = in-lane + shfl_xor(16);
// softmax over to: exp-sums via bufX [ti][px*12+wv] (bank-conflict-free).
template<bool PACKED>
__global__ __launch_bounds__(512, 4)
void caps_main(const float* __restrict__ x, const float* __restrict__ w,
               const _Float16* __restrict__ wpk,
               const float* __restrict__ cbias, const float* __restrict__ rbias,
               float* __restrict__ out)
{
    __shared__ alignas(16) float lds[LDS_F];
    _Float16* xt  = (_Float16*)lds;
    float* bufS   = lds + BUFS_OFF;
    float* vbuf   = lds + VB_OFF;

    const int tid  = threadIdx.x;
    const int lane = tid & 63;
    const int wv   = tid >> 6;          // 0..7 = M-tile
    const int px16 = lane & 15;
    const int q    = lane >> 4;         // 0..3

    // XCD-aware bijective swizzle: 1984 = 8 * 248
    const int bid  = blockIdx.x;
    const int work = (bid & 7) * 248 + (bid >> 3);
    const int n    = work / 248;
    const int rem  = work - n * 248;
    const int ho   = rem >> 2;
    const int wo0  = (rem & 3) << 4;

    // A-fragment loader (all call sites have compile-time ti/ks)
    const half8* wA = (const half8*)wpk;
    auto loadA = [&](int ti, int ks) -> half8 {
        if (PACKED) {
            return wA[ti * 1536 + wv * 192 + ks * 64 + lane];
        } else {
            half8 af = {};
            const float* wr = w + (size_t)(ti * 128 + wv * 16 + px16) * 72;
            int kb = ks * 32 + q * 8;
            #pragma unroll
            for (int j = 0; j < 8; ++j) {
                int kp = kb + j;
                if (kp < 72) {
                    int kw2 = kp / 24, rem2 = kp - kw2 * 24;
                    af[j] = (_Float16)wr[rem2 * 3 + kw2];
                }
            }
            return af;
        }
    };

    // ---- issue ks=0 A-loads NOW: latency hides under staging + barrier ------
    half8 A0[8], A1[8];
    #pragma unroll
    for (int ti = 0; ti < 8; ++ti) A0[ti] = loadA(ti, 0);

    // ---- stage x -> f16 transposed patch xt[col][row], row-quad b64 writes --
    {
        const float* xb = x + (size_t)n * 262144;
        for (int t = tid; t < 960; t += 512) {     // 48 row-quads * 20 cols
            int rq  = t / 20;
            int col = t - rq * 20;
            bool valid = (col < 18) && (wo0 + col < 64);
            half4v d;
            #pragma unroll
            for (int rr = 0; rr < 4; ++rr) {
                int row  = rq * 4 + rr;            // (ti*8+di)*3 + kh
                int tidi = row / 3;
                int kh   = row - tidi * 3;
                float v  = valid
                         ? xb[(size_t)tidi * 4096 + (ho + kh) * 64 + wo0 + col]
                         : 0.f;
                d[rr] = (_Float16)v;
            }
            *(half4v*)(xt + col * XT_STR + rq * 4) = d;
        }
    }
    __syncthreads();

    // ---------------- MFMA conv, A-pipelined: acc[ti] = uhat in regs ---------
    f32x4 acc[8];
    #pragma unroll
    for (int ti = 0; ti < 8; ++ti) acc[ti] = (f32x4){0.f, 0.f, 0.f, 0.f};

#define MFMA_STAGE(KS, ABUF)                                                   \
    {                                                                          \
        const int kb  = (KS) * 32 + q * 8;                                     \
        const int kw  = kb / 24;                                               \
        const int kbm = kb - kw * 24;                                          \
        const _Float16* bbase = xt + (px16 + kw) * XT_STR + kbm;               \
        _Pragma("unroll")                                                      \
        for (int ti = 0; ti < 8; ++ti) {                                       \
            half8 bf = *(const half8*)(bbase + ti * 24);                       \
            acc[ti] = __builtin_amdgcn_mfma_f32_16x16x32_f16(                  \
                ABUF[ti], bf, acc[ti], 0, 0, 0);                               \
        }                                                                      \
    }

    // ks=0: prefetch ks=1, compute with A0
    #pragma unroll
    for (int ti = 0; ti < 8; ++ti) A1[ti] = loadA(ti, 1);
    MFMA_STAGE(0, A0)
    // ks=1: prefetch ks=2 into A0, compute with A1
    #pragma unroll
    for (int ti = 0; ti < 8; ++ti) A0[ti] = loadA(ti, 2);
    MFMA_STAGE(1, A1)
    // ks=2: compute with A0
    MFMA_STAGE(2, A0)
#undef MFMA_STAGE

    // fold conv bias (ch = wv*16 + q*4 + r)
    #pragma unroll
    for (int ti = 0; ti < 8; ++ti) {
        float4 cb4 = *(const float4*)(cbias + ti * 128 + wv * 16 + q * 4);
        acc[ti][0] += cb4.x; acc[ti][1] += cb4.y;
        acc[ti][2] += cb4.z; acc[ti][3] += cb4.w;
    }
    const float4 rb4 = *(const float4*)(rbias + wv * 16 + q * 4);

    // ---------------- dynamic routing in conv layout -------------------------
    float breg[8];
    #pragma unroll
    for (int t = 0; t < 8; ++t) breg[t] = 0.f;

    f32x4 v = {0.f, 0.f, 0.f, 0.f};

    #pragma unroll
    for (int r = 0; r < 3; ++r) {
        f32x4 s = {rb4.x, rb4.y, rb4.z, rb4.w};

        if (r == 0) {
            // b == 0 -> c = 1/16 exactly
            #pragma unroll
            for (int ti = 0; ti < 8; ++ti) {
                s[0] = fmaf(0.0625f, acc[ti][0], s[0]);
                s[1] = fmaf(0.0625f, acc[ti][1], s[1]);
                s[2] = fmaf(0.0625f, acc[ti][2], s[2]);
                s[3] = fmaf(0.0625f, acc[ti][3], s[3]);
            }
        } else {
            float* bufX = bufS + (r - 1) * 1536;   // [ti][px*12 + wv]
            float e[8];
            #pragma unroll
            for (int ti = 0; ti < 8; ++ti) {
                e[ti] = __expf(breg[ti]);
                float Sw = e[ti] + __shfl_xor(e[ti], 32);   // both to's of wave
                if (q == 0) bufX[ti * 192 + px16 * 12 + wv] = Sw;
            }
            __syncthreads();
            #pragma unroll
            for (int ti = 0; ti < 8; ++ti) {
                f32x4 za = *(const f32x4*)(bufX + ti * 192 + px16 * 12);
                f32x4 zb = *(const f32x4*)(bufX + ti * 192 + px16 * 12 + 4);
                float Z = ((za[0] + za[1]) + (za[2] + za[3]))
                        + ((zb[0] + zb[1]) + (zb[2] + zb[3]));
                float c = __fdividef(e[ti], Z);
                s[0] = fmaf(c, acc[ti][0], s[0]);
                s[1] = fmaf(c, acc[ti][1], s[1]);
                s[2] = fmaf(c, acc[ti][2], s[2]);
                s[3] = fmaf(c, acc[ti][3], s[3]);
            }
        }

        // squash over do: in-lane (r) + shfl_xor(16) (q&1)
        float n2 = s[0] * s[0] + s[1] * s[1] + s[2] * s[2] + s[3] * s[3];
        n2 += __shfl_xor(n2, 16);
        float sc = n2 / (1.f + n2) * rsqrtf(n2 + 1e-9f);
        v[0] = s[0] * sc; v[1] = s[1] * sc; v[2] = s[2] * sc; v[3] = s[3] * sc;

        if (r < 2) {
            // agreement: b[ti][to] += sum_do uh*v
            #pragma unroll
            for (int ti = 0; ti < 8; ++ti) {
                float a = acc[ti][0] * v[0] + acc[ti][1] * v[1]
                        + acc[ti][2] * v[2] + acc[ti][3] * v[3];
                a += __shfl_xor(a, 16);
                breg[ti] += a;
            }
        }
    }

    // ---------------- output: transpose via vbuf then coalesced store --------
    {
        const int chb = wv * 16 + q * 4;
        vbuf[(chb + 0) * 20 + px16] = v[0];
        vbuf[(chb + 1) * 20 + px16] = v[1];
        vbuf[(chb + 2) * 20 + px16] = v[2];
        vbuf[(chb + 3) * 20 + px16] = v[3];
    }
    __syncthreads();
    {
        int ch  = tid >> 2;
        int jb  = (tid & 3) * 4;
        int wc0 = wo0 + jb;
        float4 vv = *(const float4*)(vbuf + ch * 20 + jb);
        size_t ob = ((size_t)(n * 128 + ch)) * 3844 + (size_t)ho * 62 + wc0;
        if (wc0 + 3 < 62) {
            out[ob + 0] = vv.x; out[ob + 1] = vv.y;
            out[ob + 2] = vv.z; out[ob + 3] = vv.w;
        } else {
            if (wc0 + 0 < 62) out[ob + 0] = vv.x;
            if (wc0 + 1 < 62) out[ob + 1] = vv.y;
            if (wc0 + 2 < 62) out[ob + 2] = vv.z;
            if (wc0 + 3 < 62) out[ob + 3] = vv.w;
        }
    }
}

extern "C" void kernel_launch(void* const* d_in, const int* in_sizes, int n_in,
                              void* d_out, int out_size, void* d_ws, size_t ws_size,
                              hipStream_t stream) {
    const float* x  = (const float*)d_in[0];
    const float* cw = (const float*)d_in[1];
    const float* cb = (const float*)d_in[2];
    const float* rb = (const float*)d_in[3];
    float* out = (float*)d_out;

    const int n_wg = N_ * HO * 4;   // 1984 = 8 XCDs * 248
    if (ws_size >= (size_t)WPACK_BYTES) {
        _Float16* wp = (_Float16*)d_ws;
        repack_w<<<(W_PAIRS + 255) / 256, 256, 0, stream>>>(cw, wp);
        caps_main<true><<<n_wg, 512, 0, stream>>>(x, cw, wp, cb, rb, out);
    } else {
        caps_main<false><<<n_wg, 512, 0, stream>>>(x, cw, nullptr, cb, rb, out);
    }
}